// Round 9
// baseline (419.842 us; speedup 1.0000x reference)
//
#include <hip/hip_runtime.h>
#include <hip/hip_fp16.h>

#define CC 256
#define HWIMG 4096
#define NPIX 131072
#define KCODES 1024
#define FULLCAP 32768
#define MARGIN 0.125f

typedef _Float16 half8 __attribute__((ext_vector_type(8)));
typedef short short8v __attribute__((ext_vector_type(8)));
typedef float f32x4 __attribute__((ext_vector_type(4)));
typedef unsigned short u16;
typedef unsigned int u32;

__device__ __forceinline__ void gld16(const void* g, void* l) {
    __builtin_amdgcn_global_load_lds(
        (const __attribute__((address_space(1))) void*)g,
        (__attribute__((address_space(3))) void*)l, 16, 0, 0);
}

// LDS/image layout (proven round-4 swizzle, K=64 pairs):
// row = 128B = 8 slots of 16B covering 64 channels (2 K=32 subchunks).
// logical slot = b*4 + kg  (b = subchunk, kg = 16B group within subchunk)
// physical slot = slot ^ (row & 7);  byte = row*128 + phys*16.

// ---------- prep_e: codebook -> fp16 pair-images [16][256 rows][128B] + esq --
__global__ __launch_bounds__(256) void prep_e(const float* __restrict__ cb,
    char* __restrict__ e_prep, float* __restrict__ esq, int* __restrict__ cnts)
{
    __shared__ u16 eh[256];
    __shared__ float red[4];
    int k = blockIdx.x, c = threadIdx.x;
    float v = cb[(size_t)k * CC + c];
    eh[c] = __half_as_ushort(__float2half(v));
    float s = v * v;
    #pragma unroll
    for (int m = 32; m; m >>= 1) s += __shfl_xor(s, m, 64);
    if ((c & 63) == 0) red[c >> 6] = s;
    __syncthreads();
    if (c == 0) {
        esq[k] = (red[0] + red[1]) + (red[2] + red[3]);
        if (k == 0) { cnts[0] = 0; cnts[1] = 0; }
    }
    if (c < 32) {                       // 4 channel-pairs (cpair) x 8 phys slots
        int cpair = c >> 3, phys = c & 7;
        int pass = k >> 8, row = k & 255;
        int slot = phys ^ (row & 7);
        int cst = cpair * 64 + (slot >> 2) * 32 + (slot & 3) * 8;
        short8v w;
        #pragma unroll
        for (int j = 0; j < 8; ++j) w[j] = (short)eh[cst + j];
        *(short8v*)(e_prep + (size_t)(pass * 4 + cpair) * 32768 + row * 128 + phys * 16) = w;
    }
}

// ---------- prep_xT: x NCHW fp32 -> fp16 pair-images (in d_out) --------------
// x_prep: [blk 2048][pi 4][8 KB: px*128 + phys*16], gld-linear-ready.
__global__ __launch_bounds__(256) void prep_xT(const float* __restrict__ x,
    char* __restrict__ x_prep)
{
    __shared__ u32 pk[64 * 261];      // [px][c] fp16 in low bits
    const int blk = blockIdx.x, t = threadIdx.x;
    const float* xb = x + (size_t)(blk >> 6) * (CC * HWIMG) + (blk & 63) * 64;
    #pragma unroll 4
    for (int p = 0; p < 16; ++p) {
        int c = p * 16 + (t >> 4);
        int px4 = (t & 15) * 4;
        float4 v = *(const float4*)&xb[(size_t)c * HWIMG + px4];
        float vv[4] = {v.x, v.y, v.z, v.w};
        #pragma unroll
        for (int i = 0; i < 4; ++i)
            pk[(px4 + i) * 261 + c] = (u32)__half_as_ushort(__float2half(vv[i]));
    }
    __syncthreads();
    char* obase = x_prep + (size_t)blk * 32768;
    #pragma unroll
    for (int i = 0; i < 8; ++i) {
        int gid = t + 256 * i;            // [pi 4][px 64][phys 8]
        int pi = gid >> 9, rem = gid & 511, px = rem >> 3, phys = rem & 7;
        int slot = phys ^ (px & 7);
        int c0 = pi * 64 + (slot >> 2) * 32 + (slot & 3) * 8;
        const u32* pr = &pk[px * 261 + c0];
        short8v ov;
        #pragma unroll
        for (int j = 0; j < 8; ++j) ov[j] = (short)(pr[j] & 0xFFFF);
        *(short8v*)(obase + pi * 8192 + px * 128 + phys * 16) = ov;
    }
}

// ---------- dist: 1-term fp16 MFMA, K=64 stage units, dbuf counted vmcnt -----
// 256 thr = 4 waves (code quarters). 16 units (pass 0..3 x cpair 0..3).
// LDS: 2 x (x 8 KB | e 32 KB) = 80 KB. 32 MFMA per barrier window.
__global__ __launch_bounds__(256, 2) void dist_kernel(
    const char* __restrict__ x_prep, const char* __restrict__ e_prep,
    const float* __restrict__ esq,
    int* __restrict__ min_idx, int* __restrict__ cnts,
    int* __restrict__ full_list)
{
    __shared__ char smem[81920];

    const int t = threadIdx.x;
    const int l = t & 63;
    const int wid = t >> 6;
    const int n0 = blockIdx.x * 64;

    const int lrow = l & 15;
    const int kg   = l >> 4;
    const int ph0  = ((kg     ) ^ (lrow & 7)) * 16 + lrow * 128;  // sub b=0
    const int ph1  = ((kg ^ 4 ) ^ (lrow & 7)) * 16 + lrow * 128;  // sub b=1 (slot=4|kg)

    const char* xsrc = x_prep + (size_t)blockIdx.x * 32768;

    float min1[16], min2[16]; int idx1[16];
    #pragma unroll
    for (int s = 0; s < 16; ++s) { min1[s] = 3.4e38f; min2[s] = 3.4e38f; idx1[s] = 0; }

    f32x4 acc[4][4];

#define STAGE(cur_, ps_) do {                                                  \
        char* bb_ = smem + (cur_) * 40960;                                     \
        const char* ex_ = xsrc + ((ps_) & 3) * 8192;                           \
        const char* ee_ = e_prep + (size_t)(ps_) * 32768;                      \
        _Pragma("unroll")                                                      \
        for (int i_ = 0; i_ < 2; ++i_)                                         \
            gld16(ex_ + i_ * 4096 + wid * 1024 + l * 16,                       \
                  bb_ + i_ * 4096 + wid * 1024);                               \
        _Pragma("unroll")                                                      \
        for (int i_ = 0; i_ < 8; ++i_)                                         \
            gld16(ee_ + i_ * 4096 + wid * 1024 + l * 16,                       \
                  bb_ + 8192 + i_ * 4096 + wid * 1024);                        \
    } while (0)

    STAGE(0, 0);
    STAGE(1, 1);

    for (int ps = 0; ps < 16; ++ps) {
        const int cur = ps & 1;
        if (ps == 15) asm volatile("s_waitcnt vmcnt(0)" ::: "memory");
        else          asm volatile("s_waitcnt vmcnt(10)" ::: "memory");
        __builtin_amdgcn_s_barrier();
        __builtin_amdgcn_sched_barrier(0);

        const char* bx = smem + cur * 40960;
        const char* be = bx + 8192;

        if ((ps & 3) == 0) {
            #pragma unroll
            for (int m = 0; m < 4; ++m)
                #pragma unroll
                for (int n = 0; n < 4; ++n) acc[m][n] = (f32x4){0.f, 0.f, 0.f, 0.f};
        }
        #pragma unroll
        for (int b = 0; b < 2; ++b) {
            const int ph = b ? ph1 : ph0;
            half8 A[4], B[4];
            #pragma unroll
            for (int n = 0; n < 4; ++n)
                B[n] = *(const half8*)(be + wid * 8192 + n * 2048 + ph);
            #pragma unroll
            for (int m = 0; m < 4; ++m)
                A[m] = *(const half8*)(bx + m * 2048 + ph);
            #pragma unroll
            for (int m = 0; m < 4; ++m)
                #pragma unroll
                for (int n = 0; n < 4; ++n)
                    acc[m][n] = __builtin_amdgcn_mfma_f32_16x16x32_f16(A[m], B[n], acc[m][n], 0, 0, 0);
        }

        if ((ps & 3) == 3) {   // pass epilogue: d = esq - 2*dot, top-2 update
            const int pass = ps >> 2;
            #pragma unroll
            for (int n = 0; n < 4; ++n) {
                int code = pass * 256 + wid * 64 + n * 16 + lrow;
                float eq = esq[code];
                #pragma unroll
                for (int m = 0; m < 4; ++m) {
                    #pragma unroll
                    for (int q = 0; q < 4; ++q) {
                        float d = fmaf(-2.0f, acc[m][n][q], eq);
                        int s = m * 4 + q;
                        if (d < min1[s]) { min2[s] = min1[s]; min1[s] = d; idx1[s] = code; }
                        else if (d < min2[s]) { min2[s] = d; }
                    }
                }
            }
        }
        __builtin_amdgcn_sched_barrier(0);
        __builtin_amdgcn_s_barrier();
        if (ps < 14) STAGE(cur, ps + 2);
    }
#undef STAGE

    // reduce across 16 code-lanes, then across the 4 waves
    float* rm1 = (float*)smem;
    float* rm2 = (float*)(smem + 1024);
    int*   rim = (int*)(smem + 2048);
    #pragma unroll
    for (int s = 0; s < 16; ++s) {
        float m1 = min1[s]; int i1 = idx1[s]; float m2 = min2[s];
        #pragma unroll
        for (int msk = 1; msk <= 8; msk <<= 1) {
            float o1 = __shfl_xor(m1, msk, 64);
            int   oi = __shfl_xor(i1, msk, 64);
            float o2 = __shfl_xor(m2, msk, 64);
            if (o1 < m1 || (o1 == m1 && oi < i1)) { m2 = fminf(fminf(m2, o2), m1); m1 = o1; i1 = oi; }
            else { m2 = fminf(fminf(m2, o2), o1); }
        }
        if (lrow == 0) {
            int px_local = (s >> 2) * 16 + (l >> 4) * 4 + (s & 3);
            rm1[wid * 64 + px_local] = m1;
            rm2[wid * 64 + px_local] = m2;
            rim[wid * 64 + px_local] = i1;
        }
    }
    __syncthreads();
    if (t < 64) {
        float m1 = rm1[t]; int i1 = rim[t]; float m2 = rm2[t];
        #pragma unroll
        for (int w = 1; w < 4; ++w) {
            float o1 = rm1[w * 64 + t]; int oi = rim[w * 64 + t]; float o2 = rm2[w * 64 + t];
            if (o1 < m1 || (o1 == m1 && oi < i1)) { m2 = fminf(fminf(m2, o2), m1); m1 = o1; i1 = oi; }
            else { m2 = fminf(fminf(m2, o2), o1); }
        }
        int n = n0 + t;
        min_idx[n] = i1;
        if (m2 - m1 <= MARGIN) {
            int slot = atomicAdd(&cnts[0], 1);
            if (slot < FULLCAP) full_list[slot] = n;
        }
    }
}

// ---------- recheck_full4: fp64 exact argmin, 4 flagged pixels per block -----
__global__ __launch_bounds__(256) void recheck_full4(
    const float* __restrict__ x, const float* __restrict__ cb,
    const int* __restrict__ cnts, const int* __restrict__ full_list,
    int* __restrict__ min_idx)
{
    __shared__ float  xs[4][CC];
    __shared__ double rbest[4][256];
    __shared__ int    ribst[4][256];
    int cnt = cnts[0]; if (cnt > FULLCAP) cnt = FULLCAP;
    int ngrp = (cnt + 3) >> 2;
    const int t = threadIdx.x;
    for (int g = blockIdx.x; g < ngrp; g += gridDim.x) {
        int npx = cnt - g * 4; if (npx > 4) npx = 4;
        for (int i = t; i < npx * 256; i += 256) {
            int p = i >> 8, c = i & 255;
            int n = full_list[g * 4 + p];
            int b = n / HWIMG, hw = n % HWIMG;
            xs[p][c] = x[(size_t)b * CC * HWIMG + (size_t)c * HWIMG + hw];
        }
        __syncthreads();
        double best[4] = {1e300, 1e300, 1e300, 1e300};
        int bi[4] = {0, 0, 0, 0};
        #pragma unroll
        for (int kk = 0; kk < 4; ++kk) {
            int k = t * 4 + kk;
            const float4* er = (const float4*)(cb + (size_t)k * CC);
            double s[4] = {0.0, 0.0, 0.0, 0.0};
            for (int c4 = 0; c4 < 64; ++c4) {
                float4 e = er[c4];
                float ea[4] = {e.x, e.y, e.z, e.w};
                #pragma unroll
                for (int j = 0; j < 4; ++j) {
                    #pragma unroll
                    for (int p = 0; p < 4; ++p) {
                        double d = (double)xs[p][c4 * 4 + j] - (double)ea[j];
                        s[p] = fma(d, d, s[p]);
                    }
                }
            }
            #pragma unroll
            for (int p = 0; p < 4; ++p)
                if (s[p] < best[p]) { best[p] = s[p]; bi[p] = k; }
        }
        #pragma unroll
        for (int p = 0; p < 4; ++p) { rbest[p][t] = best[p]; ribst[p][t] = bi[p]; }
        __syncthreads();
        for (int st = 128; st; st >>= 1) {
            if (t < st) {
                #pragma unroll
                for (int p = 0; p < 4; ++p) {
                    double ov = rbest[p][t + st]; int oi = ribst[p][t + st];
                    if (ov < rbest[p][t] || (ov == rbest[p][t] && oi < ribst[p][t])) {
                        rbest[p][t] = ov; ribst[p][t] = oi;
                    }
                }
            }
            __syncthreads();
        }
        if (t < npx) min_idx[full_list[g * 4 + t]] = ribst[t][0];
        __syncthreads();
    }
}

// ---------- out: gather quantized (NCHW) + fp64 loss partials ----------------
__global__ __launch_bounds__(256) void out_kernel(
    const float* __restrict__ x, const float* __restrict__ cb,
    const int* __restrict__ min_idx, float* __restrict__ out,
    double* __restrict__ partials)
{
    int n = blockIdx.x * 256 + threadIdx.x;
    int b = n / HWIMG, hw = n % HWIMG;
    const float* xb = x + (size_t)b * CC * HWIMG + hw;
    float*       ob = out + (size_t)b * CC * HWIMG + hw;
    int k = min_idx[n];
    const float* er = cb + (size_t)k * CC;
    double ls = 0.0;
    #pragma unroll 4
    for (int c = 0; c < CC; c += 4) {
        float4 q = *(const float4*)&er[c];
        float x0 = xb[(size_t)(c + 0) * HWIMG];
        float x1 = xb[(size_t)(c + 1) * HWIMG];
        float x2 = xb[(size_t)(c + 2) * HWIMG];
        float x3 = xb[(size_t)(c + 3) * HWIMG];
        ob[(size_t)(c + 0) * HWIMG] = q.x;
        ob[(size_t)(c + 1) * HWIMG] = q.y;
        ob[(size_t)(c + 2) * HWIMG] = q.z;
        ob[(size_t)(c + 3) * HWIMG] = q.w;
        double d0 = (double)q.x - (double)x0;
        double d1 = (double)q.y - (double)x1;
        double d2 = (double)q.z - (double)x2;
        double d3 = (double)q.w - (double)x3;
        ls += d0 * d0 + d1 * d1 + d2 * d2 + d3 * d3;
    }
    __shared__ double sred[256];
    sred[threadIdx.x] = ls;
    __syncthreads();
    for (int s = 128; s; s >>= 1) {
        if (threadIdx.x < (unsigned)s) sred[threadIdx.x] += sred[threadIdx.x + s];
        __syncthreads();
    }
    if (threadIdx.x == 0) partials[blockIdx.x] = sred[0];
}

__global__ void loss_kernel(const double* __restrict__ partials, float* __restrict__ out)
{
    if (threadIdx.x == 0 && blockIdx.x == 0) {
        double s = 0.0;
        for (int i = 0; i < 512; i++) s += partials[i];
        out[33554432] = (float)(1.25 * s / 33554432.0);
    }
}

// ---------- launch -----------------------------------------------------------
extern "C" void kernel_launch(void* const* d_in, const int* in_sizes, int n_in,
                              void* d_out, int out_size, void* d_ws, size_t ws_size,
                              hipStream_t stream)
{
    const float* x  = (const float*)d_in[0];
    const float* cb = (const float*)d_in[1];
    float* out = (float*)d_out;

    // x_prep (64 MB) lives in d_out; out_kernel rewrites d_out afterwards.
    char* x_prep = (char*)d_out;

    char* ws = (char*)d_ws;
    char*   e_prep    = (char*) (ws + 0);            //   524,288 B
    float*  esq       = (float*)(ws + 524288);       //     4,096 B
    int*    min_idx   = (int*)  (ws + 528384);       //   524,288 B
    int*    cnts      = (int*)  (ws + 1052672);      //        16 B
    int*    full_list = (int*)  (ws + 1052688);      //   131,072 B
    double* partials  = (double*)(ws + 1183760);     //     4,096 B

    prep_e       <<<KCODES, 256, 0, stream>>>(cb, e_prep, esq, cnts);
    prep_xT      <<<NPIX / 64, 256, 0, stream>>>(x, x_prep);
    dist_kernel  <<<NPIX / 64, 256, 0, stream>>>(x_prep, e_prep, esq,
                                                 min_idx, cnts, full_list);
    recheck_full4<<<1024, 256, 0, stream>>>(x, cb, cnts, full_list, min_idx);
    out_kernel   <<<NPIX / 256, 256, 0, stream>>>(x, cb, min_idx, out, partials);
    loss_kernel  <<<1, 64, 0, stream>>>(partials, out);
}

// Round 10
// 395.087 us; speedup vs baseline: 1.0627x; 1.0627x over previous
//
#include <hip/hip_runtime.h>
#include <hip/hip_fp16.h>

#define CC 256
#define HWIMG 4096
#define NPIX 131072
#define KCODES 1024
#define FULLCAP 32768
#define MARGIN 0.125f

typedef _Float16 half8 __attribute__((ext_vector_type(8)));
typedef short short8v __attribute__((ext_vector_type(8)));
typedef float f32x4 __attribute__((ext_vector_type(4)));
typedef unsigned short u16;
typedef unsigned int u32;

__device__ __forceinline__ void gld16(const void* g, void* l) {
    __builtin_amdgcn_global_load_lds(
        (const __attribute__((address_space(1))) void*)g,
        (__attribute__((address_space(3))) void*)l, 16, 0, 0);
}

// ---------- prep_e: codebook -> fp16 frag-major image + esq ------------------
// e_frag[cg 64][kc 8][lane 64]*16B : lane l of frag (cg,kc) holds
// codebook[cg*16 + (l&15)][kc*32 + (l>>4)*8 + j], j=0..7.
__global__ __launch_bounds__(256) void prep_e(const float* __restrict__ cb,
    char* __restrict__ e_frag, float* __restrict__ esq, int* __restrict__ cnts)
{
    __shared__ u16 eh[256];
    __shared__ float red[4];
    int k = blockIdx.x, c = threadIdx.x;
    float v = cb[(size_t)k * CC + c];
    eh[c] = __half_as_ushort(__float2half(v));
    float s = v * v;
    #pragma unroll
    for (int m = 32; m; m >>= 1) s += __shfl_xor(s, m, 64);
    if ((c & 63) == 0) red[c >> 6] = s;
    __syncthreads();
    if (c == 0) {
        esq[k] = (red[0] + red[1]) + (red[2] + red[3]);
        if (k == 0) { cnts[0] = 0; cnts[1] = 0; }
    }
    if (c < 32) {                       // kc = c>>2, kq = c&3
        int kc = c >> 2, kq = c & 3;
        short8v w;
        #pragma unroll
        for (int j = 0; j < 8; ++j) w[j] = (short)eh[kc * 32 + kq * 8 + j];
        size_t off = ((((size_t)(k >> 4) * 8 + kc) * 64) + kq * 16 + (k & 15)) * 16;
        *(short8v*)(e_frag + off) = w;
    }
}

// ---------- prep_xT: x NCHW fp32 -> fp16 pair-images (in d_out) --------------
// x_prep: [blk 2048][pi 4][8 KB: px*128 + phys*16]; phys = slot ^ (px & 7),
// slot = b*4+kg covering ch pi*64 + b*32 + kg*8 .. +8.
__global__ __launch_bounds__(256) void prep_xT(const float* __restrict__ x,
    char* __restrict__ x_prep)
{
    __shared__ u32 pk[64 * 261];      // [px][c] fp16 in low bits
    const int blk = blockIdx.x, t = threadIdx.x;
    const float* xb = x + (size_t)(blk >> 6) * (CC * HWIMG) + (blk & 63) * 64;
    #pragma unroll 4
    for (int p = 0; p < 16; ++p) {
        int c = p * 16 + (t >> 4);
        int px4 = (t & 15) * 4;
        float4 v = *(const float4*)&xb[(size_t)c * HWIMG + px4];
        float vv[4] = {v.x, v.y, v.z, v.w};
        #pragma unroll
        for (int i = 0; i < 4; ++i)
            pk[(px4 + i) * 261 + c] = (u32)__half_as_ushort(__float2half(vv[i]));
    }
    __syncthreads();
    char* obase = x_prep + (size_t)blk * 32768;
    #pragma unroll
    for (int i = 0; i < 8; ++i) {
        int gid = t + 256 * i;            // [pi 4][px 64][phys 8]
        int pi = gid >> 9, rem = gid & 511, px = rem >> 3, phys = rem & 7;
        int slot = phys ^ (px & 7);
        int c0 = pi * 64 + (slot >> 2) * 32 + (slot & 3) * 8;
        const u32* pr = &pk[px * 261 + c0];
        short8v ov;
        #pragma unroll
        for (int j = 0; j < 8; ++j) ov[j] = (short)(pr[j] & 0xFFFF);
        *(short8v*)(obase + pi * 8192 + px * 128 + phys * 16) = ov;
    }
}

// ---------- dist: B-stationary 1-term fp16 MFMA --------------------------------
// Grid 512 = slice(4, slow) x pxr(128). Block: 4 waves, wave owns 64 codes
// (slice*256 + wid*64) held in registers (32 frags). Loop 16 px-tiles of 64 px;
// stage x-tile (32 KB) dbuf via gld16, counted vmcnt(8). 128 MFMA / 32 ds_read.
__global__ __launch_bounds__(256, 2) void dist_kernel(
    const char* __restrict__ x_prep, const char* __restrict__ e_frag,
    const float* __restrict__ esq,
    float2* __restrict__ pm, int* __restrict__ pidx)
{
    __shared__ char smem[65536];

    const int t = threadIdx.x;
    const int l = t & 63;
    const int wid = t >> 6;
    const int slice = blockIdx.x >> 7;
    const int pxr   = blockIdx.x & 127;

    const int lrow = l & 15;
    const int kg   = l >> 4;
    const int ph0  = ((kg    ) ^ (lrow & 7)) * 16 + lrow * 128;  // slot=kg
    const int ph1  = ((kg ^ 4) ^ (lrow & 7)) * 16 + lrow * 128;  // slot=4+kg

    const char* xsrc = x_prep + (size_t)pxr * 16 * 32768;
    const int codebase = slice * 256 + wid * 64;
    const int j = slice * 4 + wid;            // partial index (code-ascending)

    // ---- load B fragments (held whole kernel): 32 x 16B coalesced ----
    half8 Breg[4][8];
    #pragma unroll
    for (int cg = 0; cg < 4; ++cg)
        #pragma unroll
        for (int kc = 0; kc < 8; ++kc)
            Breg[cg][kc] = *(const half8*)(e_frag +
                ((((size_t)(slice * 16 + wid * 4 + cg) * 8 + kc) * 64 + l) * 16));

    float eqv[4];
    #pragma unroll
    for (int n = 0; n < 4; ++n) eqv[n] = esq[codebase + n * 16 + lrow];

#define STAGE(cur_, pt_) do {                                                  \
        const char* sx_ = xsrc + (size_t)(pt_) * 32768;                        \
        char* bb_ = smem + (cur_) * 32768;                                     \
        _Pragma("unroll")                                                      \
        for (int i_ = 0; i_ < 8; ++i_)                                         \
            gld16(sx_ + i_ * 4096 + wid * 1024 + l * 16,                       \
                  bb_ + i_ * 4096 + wid * 1024);                               \
    } while (0)

    STAGE(0, 0);
    STAGE(1, 1);

    for (int pt = 0; pt < 16; ++pt) {
        const int cur = pt & 1;
        if (pt == 15) asm volatile("s_waitcnt vmcnt(0)" ::: "memory");
        else          asm volatile("s_waitcnt vmcnt(8)" ::: "memory");
        __builtin_amdgcn_s_barrier();
        __builtin_amdgcn_sched_barrier(0);

        const char* bx = smem + cur * 32768;

        f32x4 acc[4][4];
        #pragma unroll
        for (int m = 0; m < 4; ++m)
            #pragma unroll
            for (int n = 0; n < 4; ++n) acc[m][n] = (f32x4){0.f, 0.f, 0.f, 0.f};

        #pragma unroll
        for (int pi = 0; pi < 4; ++pi) {
            #pragma unroll
            for (int b = 0; b < 2; ++b) {
                const int ph = b ? ph1 : ph0;
                const int kc = pi * 2 + b;
                half8 A[4];
                #pragma unroll
                for (int m = 0; m < 4; ++m)
                    A[m] = *(const half8*)(bx + pi * 8192 + m * 2048 + ph);
                #pragma unroll
                for (int m = 0; m < 4; ++m)
                    #pragma unroll
                    for (int n = 0; n < 4; ++n)
                        acc[m][n] = __builtin_amdgcn_mfma_f32_16x16x32_f16(
                            A[m], Breg[n][kc], acc[m][n], 0, 0, 0);
            }
        }

        // epilogue: d = esq - 2*dot; top-2 over this wave's 64 codes per px
        const int nbase = (pxr * 16 + pt) * 64;
        #pragma unroll
        for (int m = 0; m < 4; ++m) {
            #pragma unroll
            for (int q = 0; q < 4; ++q) {
                float m1, m2; int i1;
                {   // local merge over n = 0..3
                    float d0 = fmaf(-2.0f, acc[m][0][q], eqv[0]);
                    m1 = d0; i1 = codebase + 0 * 16 + lrow; m2 = 3.4e38f;
                    #pragma unroll
                    for (int n = 1; n < 4; ++n) {
                        float d = fmaf(-2.0f, acc[m][n][q], eqv[n]);
                        int cd = codebase + n * 16 + lrow;
                        if (d < m1) { m2 = m1; m1 = d; i1 = cd; }
                        else if (d < m2) { m2 = d; }
                    }
                }
                // reduce over the 16 lrow lanes
                #pragma unroll
                for (int msk = 1; msk <= 8; msk <<= 1) {
                    float o1 = __shfl_xor(m1, msk, 64);
                    int   oi = __shfl_xor(i1, msk, 64);
                    float o2 = __shfl_xor(m2, msk, 64);
                    if (o1 < m1 || (o1 == m1 && oi < i1)) {
                        m2 = fminf(fminf(m2, o2), m1); m1 = o1; i1 = oi;
                    } else {
                        m2 = fminf(fminf(m2, o2), o1);
                    }
                }
                if (lrow == 0) {
                    int n = nbase + m * 16 + kg * 4 + q;
                    pm[(size_t)j * NPIX + n] = make_float2(m1, m2);
                    pidx[(size_t)j * NPIX + n] = i1;
                }
            }
        }
        __builtin_amdgcn_sched_barrier(0);
        __builtin_amdgcn_s_barrier();
        if (pt < 14) STAGE(cur, pt + 2);
    }
#undef STAGE
}

// ---------- merge: 16 partials per px -> min_idx + flag ----------------------
__global__ __launch_bounds__(256) void merge_kernel(
    const float2* __restrict__ pm, const int* __restrict__ pidx,
    int* __restrict__ min_idx, int* __restrict__ cnts,
    int* __restrict__ full_list)
{
    int n = blockIdx.x * 256 + threadIdx.x;
    float m1 = 3.4e38f, m2 = 3.4e38f; int i1 = 0;
    #pragma unroll
    for (int j = 0; j < 16; ++j) {        // j ascending == code ascending
        float2 p = pm[(size_t)j * NPIX + n];
        int    bi = pidx[(size_t)j * NPIX + n];
        if (p.x < m1) { m2 = fminf(m1, p.y); m1 = p.x; i1 = bi; }
        else          { m2 = fminf(m2, p.x); }
    }
    min_idx[n] = i1;
    if (m2 - m1 <= MARGIN) {
        int slot = atomicAdd(&cnts[0], 1);
        if (slot < FULLCAP) full_list[slot] = n;
    }
}

// ---------- recheck_full4: fp64 exact argmin, 4 flagged pixels per block -----
__global__ __launch_bounds__(256) void recheck_full4(
    const float* __restrict__ x, const float* __restrict__ cb,
    const int* __restrict__ cnts, const int* __restrict__ full_list,
    int* __restrict__ min_idx)
{
    __shared__ float  xs[4][CC];
    __shared__ double rbest[4][256];
    __shared__ int    ribst[4][256];
    int cnt = cnts[0]; if (cnt > FULLCAP) cnt = FULLCAP;
    int ngrp = (cnt + 3) >> 2;
    const int t = threadIdx.x;
    for (int g = blockIdx.x; g < ngrp; g += gridDim.x) {
        int npx = cnt - g * 4; if (npx > 4) npx = 4;
        for (int i = t; i < npx * 256; i += 256) {
            int p = i >> 8, c = i & 255;
            int n = full_list[g * 4 + p];
            int b = n / HWIMG, hw = n % HWIMG;
            xs[p][c] = x[(size_t)b * CC * HWIMG + (size_t)c * HWIMG + hw];
        }
        __syncthreads();
        double best[4] = {1e300, 1e300, 1e300, 1e300};
        int bi[4] = {0, 0, 0, 0};
        #pragma unroll
        for (int kk = 0; kk < 4; ++kk) {
            int k = t * 4 + kk;
            const float4* er = (const float4*)(cb + (size_t)k * CC);
            double s[4] = {0.0, 0.0, 0.0, 0.0};
            for (int c4 = 0; c4 < 64; ++c4) {
                float4 e = er[c4];
                float ea[4] = {e.x, e.y, e.z, e.w};
                #pragma unroll
                for (int jj = 0; jj < 4; ++jj) {
                    #pragma unroll
                    for (int p = 0; p < 4; ++p) {
                        double d = (double)xs[p][c4 * 4 + jj] - (double)ea[jj];
                        s[p] = fma(d, d, s[p]);
                    }
                }
            }
            #pragma unroll
            for (int p = 0; p < 4; ++p)
                if (s[p] < best[p]) { best[p] = s[p]; bi[p] = k; }
        }
        #pragma unroll
        for (int p = 0; p < 4; ++p) { rbest[p][t] = best[p]; ribst[p][t] = bi[p]; }
        __syncthreads();
        for (int st = 128; st; st >>= 1) {
            if (t < st) {
                #pragma unroll
                for (int p = 0; p < 4; ++p) {
                    double ov = rbest[p][t + st]; int oi = ribst[p][t + st];
                    if (ov < rbest[p][t] || (ov == rbest[p][t] && oi < ribst[p][t])) {
                        rbest[p][t] = ov; ribst[p][t] = oi;
                    }
                }
            }
            __syncthreads();
        }
        if (t < npx) min_idx[full_list[g * 4 + t]] = ribst[t][0];
        __syncthreads();
    }
}

// ---------- out: gather quantized (NCHW) + fp64 loss partials ----------------
__global__ __launch_bounds__(256) void out_kernel(
    const float* __restrict__ x, const float* __restrict__ cb,
    const int* __restrict__ min_idx, float* __restrict__ out,
    double* __restrict__ partials)
{
    int n = blockIdx.x * 256 + threadIdx.x;
    int b = n / HWIMG, hw = n % HWIMG;
    const float* xb = x + (size_t)b * CC * HWIMG + hw;
    float*       ob = out + (size_t)b * CC * HWIMG + hw;
    int k = min_idx[n];
    const float* er = cb + (size_t)k * CC;
    double ls = 0.0;
    #pragma unroll 4
    for (int c = 0; c < CC; c += 4) {
        float4 q = *(const float4*)&er[c];
        float x0 = xb[(size_t)(c + 0) * HWIMG];
        float x1 = xb[(size_t)(c + 1) * HWIMG];
        float x2 = xb[(size_t)(c + 2) * HWIMG];
        float x3 = xb[(size_t)(c + 3) * HWIMG];
        ob[(size_t)(c + 0) * HWIMG] = q.x;
        ob[(size_t)(c + 1) * HWIMG] = q.y;
        ob[(size_t)(c + 2) * HWIMG] = q.z;
        ob[(size_t)(c + 3) * HWIMG] = q.w;
        double d0 = (double)q.x - (double)x0;
        double d1 = (double)q.y - (double)x1;
        double d2 = (double)q.z - (double)x2;
        double d3 = (double)q.w - (double)x3;
        ls += d0 * d0 + d1 * d1 + d2 * d2 + d3 * d3;
    }
    __shared__ double sred[256];
    sred[threadIdx.x] = ls;
    __syncthreads();
    for (int s = 128; s; s >>= 1) {
        if (threadIdx.x < (unsigned)s) sred[threadIdx.x] += sred[threadIdx.x + s];
        __syncthreads();
    }
    if (threadIdx.x == 0) partials[blockIdx.x] = sred[0];
}

__global__ void loss_kernel(const double* __restrict__ partials, float* __restrict__ out)
{
    if (threadIdx.x == 0 && blockIdx.x == 0) {
        double s = 0.0;
        for (int i = 0; i < 512; i++) s += partials[i];
        out[33554432] = (float)(1.25 * s / 33554432.0);
    }
}

// ---------- launch -----------------------------------------------------------
extern "C" void kernel_launch(void* const* d_in, const int* in_sizes, int n_in,
                              void* d_out, int out_size, void* d_ws, size_t ws_size,
                              hipStream_t stream)
{
    const float* x  = (const float*)d_in[0];
    const float* cb = (const float*)d_in[1];
    float* out = (float*)d_out;

    // d_out scratch map: x_prep [0,64MB) | pm [64,80MB) | pidx [80,88MB).
    // out_kernel rewrites all of d_out afterwards.
    char*   x_prep = (char*)d_out;
    float2* pm     = (float2*)(x_prep + 67108864);
    int*    pidx   = (int*)   (x_prep + 67108864 + 16777216);

    char* ws = (char*)d_ws;
    char*   e_frag    = (char*) (ws + 0);            //   524,288 B
    float*  esq       = (float*)(ws + 524288);       //     4,096 B
    int*    min_idx   = (int*)  (ws + 528384);       //   524,288 B
    int*    cnts      = (int*)  (ws + 1052672);      //        16 B
    int*    full_list = (int*)  (ws + 1052688);      //   131,072 B
    double* partials  = (double*)(ws + 1183760);     //     4,096 B

    prep_e       <<<KCODES, 256, 0, stream>>>(cb, e_frag, esq, cnts);
    prep_xT      <<<NPIX / 64, 256, 0, stream>>>(x, x_prep);
    dist_kernel  <<<512, 256, 0, stream>>>(x_prep, e_frag, esq, pm, pidx);
    merge_kernel <<<NPIX / 256, 256, 0, stream>>>(pm, pidx, min_idx, cnts, full_list);
    recheck_full4<<<1024, 256, 0, stream>>>(x, cb, cnts, full_list, min_idx);
    out_kernel   <<<NPIX / 256, 256, 0, stream>>>(x, cb, min_idx, out, partials);
    loss_kernel  <<<1, 64, 0, stream>>>(partials, out);
}

// Round 14
// 295.138 us; speedup vs baseline: 1.4225x; 1.3387x over previous
//
#include <hip/hip_runtime.h>
#include <hip/hip_fp16.h>

#define CC 256
#define HWIMG 4096
#define NPIX 131072
#define KCODES 1024
#define FULLCAP 32768
#define MARGIN 0.125f

typedef _Float16 half8 __attribute__((ext_vector_type(8)));
typedef short short8v __attribute__((ext_vector_type(8)));
typedef float f32x4 __attribute__((ext_vector_type(4)));
typedef unsigned short u16;
typedef unsigned int u32;

__device__ __forceinline__ void gld16(const void* g, void* l) {
    __builtin_amdgcn_global_load_lds(
        (const __attribute__((address_space(1))) void*)g,
        (__attribute__((address_space(3))) void*)l, 16, 0, 0);
}

// e image (round-9 proven layout): [pass 4][cpair 4][256 rows][128B];
// row = code&255; 8 slots of 16B; slot = b*4+kg covers ch cpair*64+b*32+kg*8;
// phys slot = slot ^ (row & 7).

// ---------- prep_e: codebook -> fp16 pair-images + esq + zero counters -------
__global__ __launch_bounds__(256) void prep_e(const float* __restrict__ cb,
    char* __restrict__ e_prep, float* __restrict__ esq, int* __restrict__ cnts)
{
    __shared__ u16 eh[256];
    __shared__ float red[4];
    int k = blockIdx.x, c = threadIdx.x;
    float v = cb[(size_t)k * CC + c];
    eh[c] = __half_as_ushort(__float2half(v));
    float s = v * v;
    #pragma unroll
    for (int m = 32; m; m >>= 1) s += __shfl_xor(s, m, 64);
    if ((c & 63) == 0) red[c >> 6] = s;
    __syncthreads();
    if (c == 0) {
        esq[k] = (red[0] + red[1]) + (red[2] + red[3]);
        if (k == 0) { cnts[0] = 0; cnts[1] = 0; }
    }
    if (c < 32) {                       // 4 channel-pairs (cpair) x 8 phys slots
        int cpair = c >> 3, phys = c & 7;
        int pass = k >> 8, row = k & 255;
        int slot = phys ^ (row & 7);
        int cst = cpair * 64 + (slot >> 2) * 32 + (slot & 3) * 8;
        short8v w;
        #pragma unroll
        for (int j = 0; j < 8; ++j) w[j] = (short)eh[cst + j];
        *(short8v*)(e_prep + (size_t)(pass * 4 + cpair) * 32768 + row * 128 + phys * 16) = w;
    }
}

// ---------- prep_xT: x NCHW fp32 -> fp16 frag-major image (in d_out) ---------
// x_frag: [pf 8192][kc 8][lane 64]*16B; lane l of frag (pf,kc) holds
// x[px = pf*16 + (l&15)][ch = kc*32 + (l>>4)*8 + j], j=0..7.
__global__ __launch_bounds__(256) void prep_xT(const float* __restrict__ x,
    char* __restrict__ x_frag)
{
    __shared__ u32 pk[64 * 261];      // [px][c] fp16 in low bits
    const int blk = blockIdx.x, t = threadIdx.x;
    const float* xb = x + (size_t)(blk >> 6) * (CC * HWIMG) + (blk & 63) * 64;
    #pragma unroll 4
    for (int p = 0; p < 16; ++p) {
        int c = p * 16 + (t >> 4);
        int px4 = (t & 15) * 4;
        float4 v = *(const float4*)&xb[(size_t)c * HWIMG + px4];
        float vv[4] = {v.x, v.y, v.z, v.w};
        #pragma unroll
        for (int i = 0; i < 4; ++i)
            pk[(px4 + i) * 261 + c] = (u32)__half_as_ushort(__float2half(vv[i]));
    }
    __syncthreads();
    char* obase = x_frag + (size_t)blk * 32768;
    #pragma unroll
    for (int i = 0; i < 8; ++i) {
        int gid = t + 256 * i;            // [f 4][kc 8][l 64]
        int l = gid & 63;
        int kc = (gid >> 6) & 7, f = gid >> 9;
        int px = f * 16 + (l & 15);
        int c0 = kc * 32 + (l >> 4) * 8;
        const u32* pr = &pk[px * 261 + c0];
        short8v ov;
        #pragma unroll
        for (int j = 0; j < 8; ++j) ov[j] = (short)(pr[j] & 0xFFFF);
        *(short8v*)(obase + gid * 16) = ov;
    }
}

// ---------- dist: x-stationary, swapped-operand fp16 MFMA, e streamed --------
// Grid 512: block = 256 px (4 waves x 64 px in registers, 32 frags/wave).
// 16 e-tiles of 64 codes; e-tile 32 KB staged dbuf via gld16, vmcnt(8).
// acc[mq=code-group][f=px-group]: lane owns pixel col=l&15, codes kg*4+q.
__global__ __launch_bounds__(256, 2) void dist_kernel(
    const char* __restrict__ x_frag, const char* __restrict__ e_prep,
    const float* __restrict__ esq_g,
    int* __restrict__ min_idx, int* __restrict__ cnts,
    int* __restrict__ full_list)
{
    __shared__ char smem[69632];          // 2 x 32KB e dbuf | 4KB esq
    char* esql = smem + 65536;

    const int t = threadIdx.x;
    const int l = t & 63;
    const int wid = t >> 6;
    const int lrow = l & 15;
    const int kg   = l >> 4;
    const int ph0  = ((kg    ) ^ (lrow & 7)) * 16 + lrow * 128;
    const int ph1  = ((kg ^ 4) ^ (lrow & 7)) * 16 + lrow * 128;
    const int pxbase = blockIdx.x * 256 + wid * 64;

    // ---- load this wave's 64 pixels as 32 MFMA B-frags (held whole kernel) --
    half8 Xreg[4][8];
    #pragma unroll
    for (int f = 0; f < 4; ++f)
        #pragma unroll
        for (int kc = 0; kc < 8; ++kc)
            Xreg[f][kc] = *(const half8*)(x_frag +
                (size_t)(((pxbase >> 4) + f) * 8 + kc) * 1024 + l * 16);
    // pin fragments in VGPRs (forbid remat-reload inside the counted-vmcnt loop)
    #pragma unroll
    for (int f = 0; f < 4; ++f)
        #pragma unroll
        for (int kc = 0; kc < 8; ++kc)
            asm volatile("" : "+v"(Xreg[f][kc]));

    // esq -> LDS: lane l copies 16B at float index wid*256 + l*4 (linear dest)
    gld16(esq_g + wid * 256 + l * 4, esql + wid * 1024);

#define STAGE(cur_, tc_) do {                                                  \
        const char* ee_ = e_prep + (size_t)((tc_) >> 2) * 131072               \
                          + ((tc_) & 3) * 8192 + wid * 32768;                  \
        char* bb_ = smem + (cur_) * 32768 + wid * 8192;                        \
        _Pragma("unroll")                                                      \
        for (int i_ = 0; i_ < 8; ++i_)                                         \
            gld16(ee_ + i_ * 1024 + l * 16, bb_ + i_ * 1024);                  \
    } while (0)

    STAGE(0, 0);
    STAGE(1, 1);

    float m1s[4], m2s[4]; int i1s[4];
    #pragma unroll
    for (int f = 0; f < 4; ++f) { m1s[f] = 3.4e38f; m2s[f] = 3.4e38f; i1s[f] = 0; }

    for (int tc = 0; tc < 16; ++tc) {
        const int cur = tc & 1;
        if (tc == 15) asm volatile("s_waitcnt vmcnt(0)" ::: "memory");
        else          asm volatile("s_waitcnt vmcnt(8)" ::: "memory");
        __builtin_amdgcn_s_barrier();
        __builtin_amdgcn_sched_barrier(0);

        const char* eL = smem + cur * 32768;

        f32x4 acc[4][4];
        #pragma unroll
        for (int mq = 0; mq < 4; ++mq)
            #pragma unroll
            for (int f = 0; f < 4; ++f) acc[mq][f] = (f32x4){0.f, 0.f, 0.f, 0.f};

        #pragma unroll
        for (int kc = 0; kc < 8; ++kc) {
            const int po = (kc >> 1) * 8192 + ((kc & 1) ? ph1 : ph0);
            half8 A[4];
            #pragma unroll
            for (int mq = 0; mq < 4; ++mq)
                A[mq] = *(const half8*)(eL + po + mq * 2048);
            #pragma unroll
            for (int mq = 0; mq < 4; ++mq)
                #pragma unroll
                for (int f = 0; f < 4; ++f)
                    acc[mq][f] = __builtin_amdgcn_mfma_f32_16x16x32_f16(
                        A[mq], Xreg[f][kc], acc[mq][f], 0, 0, 0);
        }

        // epilogue: in-lane top-2 (lane owns pixel lrow; codes = kg*4+q)
        #pragma unroll
        for (int mq = 0; mq < 4; ++mq) {
            float4 eqv = *(const float4*)(esql + (tc * 64 + mq * 16 + kg * 4) * 4);
            float eqa[4] = {eqv.x, eqv.y, eqv.z, eqv.w};
            const int cb0 = tc * 64 + mq * 16 + kg * 4;
            #pragma unroll
            for (int f = 0; f < 4; ++f) {
                #pragma unroll
                for (int q = 0; q < 4; ++q) {
                    float d = fmaf(-2.0f, acc[mq][f][q], eqa[q]);
                    if (d < m1s[f]) { m2s[f] = m1s[f]; m1s[f] = d; i1s[f] = cb0 + q; }
                    else if (d < m2s[f]) { m2s[f] = d; }
                }
            }
        }
        __builtin_amdgcn_sched_barrier(0);
        __builtin_amdgcn_s_barrier();
        if (tc < 14) STAGE(cur, tc + 2);
    }
#undef STAGE

    // final: merge the 4 kg-lanes per pixel (lanes l, l^16, l^32, l^48)
    #pragma unroll
    for (int f = 0; f < 4; ++f) {
        float m1 = m1s[f], m2 = m2s[f]; int i1 = i1s[f];
        #pragma unroll
        for (int msk = 16; msk <= 32; msk <<= 1) {
            float o1 = __shfl_xor(m1, msk, 64);
            int   oi = __shfl_xor(i1, msk, 64);
            float o2 = __shfl_xor(m2, msk, 64);
            if (o1 < m1 || (o1 == m1 && oi < i1)) {
                m2 = fminf(fminf(m2, o2), m1); m1 = o1; i1 = oi;
            } else {
                m2 = fminf(fminf(m2, o2), o1);
            }
        }
        if (kg == 0) {
            int n = pxbase + f * 16 + lrow;
            min_idx[n] = i1;
            if (m2 - m1 <= MARGIN) {
                int slot = atomicAdd(&cnts[0], 1);
                if (slot < FULLCAP) full_list[slot] = n;
            }
        }
    }
}

// ---------- recheck_full4: fp64 exact argmin, 4 flagged pixels per block -----
__global__ __launch_bounds__(256) void recheck_full4(
    const float* __restrict__ x, const float* __restrict__ cb,
    const int* __restrict__ cnts, const int* __restrict__ full_list,
    int* __restrict__ min_idx)
{
    __shared__ float  xs[4][CC];
    __shared__ double rbest[4][256];
    __shared__ int    ribst[4][256];
    int cnt = cnts[0]; if (cnt > FULLCAP) cnt = FULLCAP;
    int ngrp = (cnt + 3) >> 2;
    const int t = threadIdx.x;
    for (int g = blockIdx.x; g < ngrp; g += gridDim.x) {
        int npx = cnt - g * 4; if (npx > 4) npx = 4;
        for (int i = t; i < npx * 256; i += 256) {
            int p = i >> 8, c = i & 255;
            int n = full_list[g * 4 + p];
            int b = n / HWIMG, hw = n % HWIMG;
            xs[p][c] = x[(size_t)b * CC * HWIMG + (size_t)c * HWIMG + hw];
        }
        __syncthreads();
        double best[4] = {1e300, 1e300, 1e300, 1e300};
        int bi[4] = {0, 0, 0, 0};
        #pragma unroll
        for (int kk = 0; kk < 4; ++kk) {
            int k = t * 4 + kk;
            const float4* er = (const float4*)(cb + (size_t)k * CC);
            double s[4] = {0.0, 0.0, 0.0, 0.0};
            for (int c4 = 0; c4 < 64; ++c4) {
                float4 e = er[c4];
                float ea[4] = {e.x, e.y, e.z, e.w};
                #pragma unroll
                for (int jj = 0; jj < 4; ++jj) {
                    #pragma unroll
                    for (int p = 0; p < 4; ++p) {
                        double d = (double)xs[p][c4 * 4 + jj] - (double)ea[jj];
                        s[p] = fma(d, d, s[p]);
                    }
                }
            }
            #pragma unroll
            for (int p = 0; p < 4; ++p)
                if (s[p] < best[p]) { best[p] = s[p]; bi[p] = k; }
        }
        #pragma unroll
        for (int p = 0; p < 4; ++p) { rbest[p][t] = best[p]; ribst[p][t] = bi[p]; }
        __syncthreads();
        for (int st = 128; st; st >>= 1) {
            if (t < st) {
                #pragma unroll
                for (int p = 0; p < 4; ++p) {
                    double ov = rbest[p][t + st]; int oi = ribst[p][t + st];
                    if (ov < rbest[p][t] || (ov == rbest[p][t] && oi < ribst[p][t])) {
                        rbest[p][t] = ov; ribst[p][t] = oi;
                    }
                }
            }
            __syncthreads();
        }
        if (t < npx) min_idx[full_list[g * 4 + t]] = ribst[t][0];
        __syncthreads();
    }
}

// ---------- out: gather quantized (NCHW) + fp64 loss partials ----------------
__global__ __launch_bounds__(256) void out_kernel(
    const float* __restrict__ x, const float* __restrict__ cb,
    const int* __restrict__ min_idx, float* __restrict__ out,
    double* __restrict__ partials)
{
    int n = blockIdx.x * 256 + threadIdx.x;
    int b = n / HWIMG, hw = n % HWIMG;
    const float* xb = x + (size_t)b * CC * HWIMG + hw;
    float*       ob = out + (size_t)b * CC * HWIMG + hw;
    int k = min_idx[n];
    const float* er = cb + (size_t)k * CC;
    double ls = 0.0;
    #pragma unroll 4
    for (int c = 0; c < CC; c += 4) {
        float4 q = *(const float4*)&er[c];
        float x0 = xb[(size_t)(c + 0) * HWIMG];
        float x1 = xb[(size_t)(c + 1) * HWIMG];
        float x2 = xb[(size_t)(c + 2) * HWIMG];
        float x3 = xb[(size_t)(c + 3) * HWIMG];
        ob[(size_t)(c + 0) * HWIMG] = q.x;
        ob[(size_t)(c + 1) * HWIMG] = q.y;
        ob[(size_t)(c + 2) * HWIMG] = q.z;
        ob[(size_t)(c + 3) * HWIMG] = q.w;
        double d0 = (double)q.x - (double)x0;
        double d1 = (double)q.y - (double)x1;
        double d2 = (double)q.z - (double)x2;
        double d3 = (double)q.w - (double)x3;
        ls += d0 * d0 + d1 * d1 + d2 * d2 + d3 * d3;
    }
    __shared__ double sred[256];
    sred[threadIdx.x] = ls;
    __syncthreads();
    for (int s = 128; s; s >>= 1) {
        if (threadIdx.x < (unsigned)s) sred[threadIdx.x] += sred[threadIdx.x + s];
        __syncthreads();
    }
    if (threadIdx.x == 0) partials[blockIdx.x] = sred[0];
}

__global__ void loss_kernel(const double* __restrict__ partials, float* __restrict__ out)
{
    if (threadIdx.x == 0 && blockIdx.x == 0) {
        double s = 0.0;
        for (int i = 0; i < 512; i++) s += partials[i];
        out[33554432] = (float)(1.25 * s / 33554432.0);
    }
}

// ---------- launch -----------------------------------------------------------
extern "C" void kernel_launch(void* const* d_in, const int* in_sizes, int n_in,
                              void* d_out, int out_size, void* d_ws, size_t ws_size,
                              hipStream_t stream)
{
    const float* x  = (const float*)d_in[0];
    const float* cb = (const float*)d_in[1];
    float* out = (float*)d_out;

    // x_frag (64 MB) lives in d_out; out_kernel rewrites d_out afterwards.
    char* x_frag = (char*)d_out;

    char* ws = (char*)d_ws;
    char*   e_prep    = (char*) (ws + 0);            //   524,288 B
    float*  esq       = (float*)(ws + 524288);       //     4,096 B
    int*    min_idx   = (int*)  (ws + 528384);       //   524,288 B
    int*    cnts      = (int*)  (ws + 1052672);      //        16 B
    int*    full_list = (int*)  (ws + 1052688);      //   131,072 B
    double* partials  = (double*)(ws + 1183760);     //     4,096 B

    prep_e       <<<KCODES, 256, 0, stream>>>(cb, e_prep, esq, cnts);
    prep_xT      <<<NPIX / 64, 256, 0, stream>>>(x, x_frag);
    dist_kernel  <<<512, 256, 0, stream>>>(x_frag, e_prep, esq,
                                           min_idx, cnts, full_list);
    recheck_full4<<<1024, 256, 0, stream>>>(x, cb, cnts, full_list, min_idx);
    out_kernel   <<<NPIX / 256, 256, 0, stream>>>(x, cb, min_idx, out, partials);
    loss_kernel  <<<1, 64, 0, stream>>>(partials, out);
}

// Round 17
// 240.885 us; speedup vs baseline: 1.7429x; 1.2252x over previous
//
#include <hip/hip_runtime.h>
#include <hip/hip_fp16.h>

#define CC 256
#define HWIMG 4096
#define NPIX 131072
#define KCODES 1024
#define FULLCAP 32768
#define KMARGIN 0.0625f   // key-space margin: (M1-M2) <= 0.0625 <=> d2-d1 <= 0.125

typedef _Float16 half8 __attribute__((ext_vector_type(8)));
typedef short short8v __attribute__((ext_vector_type(8)));
typedef float f32x4 __attribute__((ext_vector_type(4)));
typedef unsigned short u16;
typedef unsigned int u32;

__device__ __forceinline__ void gld16(const void* g, void* l) {
    __builtin_amdgcn_global_load_lds(
        (const __attribute__((address_space(1))) void*)g,
        (__attribute__((address_space(3))) void*)l, 16, 0, 0);
}

// e image: [pass 4][cpair 4][256 rows][128B]; row = code&255; 8 slots of 16B;
// slot = b*4+kg covers ch cpair*64+b*32+kg*8; phys slot = slot ^ (row & 7).

// ---------- prep_e: codebook -> fp16 pair-images + (-esq/2) + zero counters --
__global__ __launch_bounds__(256) void prep_e(const float* __restrict__ cb,
    char* __restrict__ e_prep, float* __restrict__ esq, int* __restrict__ cnts)
{
    __shared__ u16 eh[256];
    __shared__ float red[4];
    int k = blockIdx.x, c = threadIdx.x;
    float v = cb[(size_t)k * CC + c];
    eh[c] = __half_as_ushort(__float2half(v));
    float s = v * v;
    #pragma unroll
    for (int m = 32; m; m >>= 1) s += __shfl_xor(s, m, 64);
    if ((c & 63) == 0) red[c >> 6] = s;
    __syncthreads();
    if (c == 0) {
        esq[k] = -0.5f * ((red[0] + red[1]) + (red[2] + red[3]));
        if (k == 0) { cnts[0] = 0; cnts[1] = 0; }
    }
    if (c < 32) {                       // 4 channel-pairs (cpair) x 8 phys slots
        int cpair = c >> 3, phys = c & 7;
        int pass = k >> 8, row = k & 255;
        int slot = phys ^ (row & 7);
        int cst = cpair * 64 + (slot >> 2) * 32 + (slot & 3) * 8;
        short8v w;
        #pragma unroll
        for (int j = 0; j < 8; ++j) w[j] = (short)eh[cst + j];
        *(short8v*)(e_prep + (size_t)(pass * 4 + cpair) * 32768 + row * 128 + phys * 16) = w;
    }
}

// ---------- prep_xT: x NCHW fp32 -> fp16 frag-major image (d_out) + xsq ------
// x_frag: [pf 8192][kc 8][lane 64]*16B; lane l of frag (pf,kc) holds
// x[px = pf*16 + (l&15)][ch = kc*32 + (l>>4)*8 + j], j=0..7.
__global__ __launch_bounds__(256) void prep_xT(const float* __restrict__ x,
    char* __restrict__ x_frag, float* __restrict__ xsq)
{
    __shared__ u32 pk[64 * 261];      // [px][c] fp16 in low bits
    __shared__ float xsq_p[256];
    const int blk = blockIdx.x, t = threadIdx.x;
    const float* xb = x + (size_t)(blk >> 6) * (CC * HWIMG) + (blk & 63) * 64;
    #pragma unroll 4
    for (int p = 0; p < 16; ++p) {
        int c = p * 16 + (t >> 4);
        int px4 = (t & 15) * 4;
        float4 v = *(const float4*)&xb[(size_t)c * HWIMG + px4];
        float vv[4] = {v.x, v.y, v.z, v.w};
        #pragma unroll
        for (int i = 0; i < 4; ++i)
            pk[(px4 + i) * 261 + c] = (u32)__half_as_ushort(__float2half(vv[i]));
    }
    __syncthreads();
    // per-pixel ||x||^2 partial (quarter channel range per thread)
    {
        int px = t & 63, qr = t >> 6;
        const u32* pr = &pk[px * 261 + qr * 64];
        float s = 0.f;
        #pragma unroll 4
        for (int c = 0; c < 64; ++c) {
            float h = __half2float(__ushort_as_half((u16)pr[c]));
            s = fmaf(h, h, s);
        }
        xsq_p[t] = s;
    }
    char* obase = x_frag + (size_t)blk * 32768;
    #pragma unroll
    for (int i = 0; i < 8; ++i) {
        int gid = t + 256 * i;            // [f 4][kc 8][l 64]
        int l = gid & 63;
        int kc = (gid >> 6) & 7, f = gid >> 9;
        int px = f * 16 + (l & 15);
        int c0 = kc * 32 + (l >> 4) * 8;
        const u32* pr = &pk[px * 261 + c0];
        short8v ov;
        #pragma unroll
        for (int j = 0; j < 8; ++j) ov[j] = (short)(pr[j] & 0xFFFF);
        *(short8v*)(obase + gid * 16) = ov;
    }
    __syncthreads();
    if (t < 64)
        xsq[blk * 64 + t] = (xsq_p[t] + xsq_p[t + 64]) + (xsq_p[t + 128] + xsq_p[t + 192]);
}

// ---------- dist: x-stationary, swapped-operand fp16 MFMA, e streamed --------
// acc init = -esq/2 -> argmin dist == argmax acc. Branch-free med3 top-2.
__global__ __launch_bounds__(256, 2) void dist_kernel(
    const char* __restrict__ x_frag, const char* __restrict__ e_prep,
    const float* __restrict__ esq_g,
    int* __restrict__ min_idx, float* __restrict__ min_d,
    int* __restrict__ cnts, int* __restrict__ full_list)
{
    __shared__ char smem[69632];          // 2 x 32KB e dbuf | 4KB (-esq/2)
    char* esql = smem + 65536;

    const int t = threadIdx.x;
    const int l = t & 63;
    const int wid = t >> 6;
    const int lrow = l & 15;
    const int kg   = l >> 4;
    const int ph0  = ((kg    ) ^ (lrow & 7)) * 16 + lrow * 128;
    const int ph1  = ((kg ^ 4) ^ (lrow & 7)) * 16 + lrow * 128;
    const int pxbase = blockIdx.x * 256 + wid * 64;

    // ---- this wave's 64 pixels as 32 MFMA B-frags (held whole kernel) ----
    half8 Xreg[4][8];
    #pragma unroll
    for (int f = 0; f < 4; ++f)
        #pragma unroll
        for (int kc = 0; kc < 8; ++kc)
            Xreg[f][kc] = *(const half8*)(x_frag +
                (size_t)(((pxbase >> 4) + f) * 8 + kc) * 1024 + l * 16);
    #pragma unroll
    for (int f = 0; f < 4; ++f)
        #pragma unroll
        for (int kc = 0; kc < 8; ++kc)
            asm volatile("" : "+v"(Xreg[f][kc]));

    // (-esq/2) -> LDS: lane l copies 16B at float index wid*256 + l*4
    gld16(esq_g + wid * 256 + l * 4, esql + wid * 1024);

#define STAGE(cur_, tc_) do {                                                  \
        const char* ee_ = e_prep + (size_t)((tc_) >> 2) * 131072               \
                          + ((tc_) & 3) * 8192 + wid * 32768;                  \
        char* bb_ = smem + (cur_) * 32768 + wid * 8192;                        \
        _Pragma("unroll")                                                      \
        for (int i_ = 0; i_ < 8; ++i_)                                         \
            gld16(ee_ + i_ * 1024 + l * 16, bb_ + i_ * 1024);                  \
    } while (0)

    STAGE(0, 0);
    STAGE(1, 1);

    float m1s[4], m2s[4]; int i1s[4];
    #pragma unroll
    for (int f = 0; f < 4; ++f) { m1s[f] = -3.4e38f; m2s[f] = -3.4e38f; i1s[f] = 0; }

    for (int tc = 0; tc < 16; ++tc) {
        const int cur = tc & 1;
        if (tc == 15) asm volatile("s_waitcnt vmcnt(0)" ::: "memory");
        else          asm volatile("s_waitcnt vmcnt(8)" ::: "memory");
        __builtin_amdgcn_s_barrier();
        __builtin_amdgcn_sched_barrier(0);

        const char* eL = smem + cur * 32768;

        f32x4 acc[4][4];
        #pragma unroll
        for (int mq = 0; mq < 4; ++mq) {
            float4 e4 = *(const float4*)(esql + (tc * 64 + mq * 16 + kg * 4) * 4);
            #pragma unroll
            for (int f = 0; f < 4; ++f)
                acc[mq][f] = (f32x4){e4.x, e4.y, e4.z, e4.w};
        }

        #pragma unroll
        for (int kc = 0; kc < 8; ++kc) {
            const int po = (kc >> 1) * 8192 + ((kc & 1) ? ph1 : ph0);
            half8 A[4];
            #pragma unroll
            for (int mq = 0; mq < 4; ++mq)
                A[mq] = *(const half8*)(eL + po + mq * 2048);
            #pragma unroll
            for (int mq = 0; mq < 4; ++mq)
                #pragma unroll
                for (int f = 0; f < 4; ++f)
                    acc[mq][f] = __builtin_amdgcn_mfma_f32_16x16x32_f16(
                        A[mq], Xreg[f][kc], acc[mq][f], 0, 0, 0);
        }

        // epilogue: branch-free in-lane top-2 over max-keys a = dot - esq/2
        #pragma unroll
        for (int mq = 0; mq < 4; ++mq) {
            const int cb0 = tc * 64 + mq * 16 + kg * 4;
            #pragma unroll
            for (int f = 0; f < 4; ++f) {
                #pragma unroll
                for (int q = 0; q < 4; ++q) {
                    float a = acc[mq][f][q];
                    float old1 = m1s[f];
                    m2s[f] = __builtin_amdgcn_fmed3f(old1, m2s[f], a);
                    bool gt = a > old1;
                    m1s[f] = fmaxf(old1, a);
                    i1s[f] = gt ? (cb0 + q) : i1s[f];
                }
            }
        }
        __builtin_amdgcn_sched_barrier(0);
        __builtin_amdgcn_s_barrier();
        if (tc < 14) STAGE(cur, tc + 2);
    }
#undef STAGE

    // final: merge the 4 kg-lanes per pixel (max-key semantics)
    #pragma unroll
    for (int f = 0; f < 4; ++f) {
        float m1 = m1s[f], m2 = m2s[f]; int i1 = i1s[f];
        #pragma unroll
        for (int msk = 16; msk <= 32; msk <<= 1) {
            float o1 = __shfl_xor(m1, msk, 64);
            int   oi = __shfl_xor(i1, msk, 64);
            float o2 = __shfl_xor(m2, msk, 64);
            if (o1 > m1 || (o1 == m1 && oi < i1)) {
                m2 = fmaxf(fmaxf(m2, o2), m1); m1 = o1; i1 = oi;
            } else {
                m2 = fmaxf(fmaxf(m2, o2), o1);
            }
        }
        if (kg == 0) {
            int n = pxbase + f * 16 + lrow;
            min_idx[n] = i1;
            min_d[n] = -2.0f * m1;       // = esq[i1] - 2*dot (for loss)
            if (m1 - m2 <= KMARGIN) {
                int slot = atomicAdd(&cnts[0], 1);
                if (slot < FULLCAP) full_list[slot] = n;
            }
        }
    }
}

// ---------- recheck_full4: fp64 exact argmin, 4 flagged pixels per block -----
__global__ __launch_bounds__(256) void recheck_full4(
    const float* __restrict__ x, const float* __restrict__ cb,
    const int* __restrict__ cnts, const int* __restrict__ full_list,
    int* __restrict__ min_idx, float* __restrict__ min_d,
    const float* __restrict__ xsq)
{
    __shared__ float  xs[4][CC];
    __shared__ double rbest[4][256];
    __shared__ int    ribst[4][256];
    int cnt = cnts[0]; if (cnt > FULLCAP) cnt = FULLCAP;
    int ngrp = (cnt + 3) >> 2;
    const int t = threadIdx.x;
    for (int g = blockIdx.x; g < ngrp; g += gridDim.x) {
        int npx = cnt - g * 4; if (npx > 4) npx = 4;
        for (int i = t; i < npx * 256; i += 256) {
            int p = i >> 8, c = i & 255;
            int n = full_list[g * 4 + p];
            int b = n / HWIMG, hw = n % HWIMG;
            xs[p][c] = x[(size_t)b * CC * HWIMG + (size_t)c * HWIMG + hw];
        }
        __syncthreads();
        double best[4] = {1e300, 1e300, 1e300, 1e300};
        int bi[4] = {0, 0, 0, 0};
        #pragma unroll
        for (int kk = 0; kk < 4; ++kk) {
            int k = t * 4 + kk;
            const float4* er = (const float4*)(cb + (size_t)k * CC);
            double s[4] = {0.0, 0.0, 0.0, 0.0};
            for (int c4 = 0; c4 < 64; ++c4) {
                float4 e = er[c4];
                float ea[4] = {e.x, e.y, e.z, e.w};
                #pragma unroll
                for (int jj = 0; jj < 4; ++jj) {
                    #pragma unroll
                    for (int p = 0; p < 4; ++p) {
                        double d = (double)xs[p][c4 * 4 + jj] - (double)ea[jj];
                        s[p] = fma(d, d, s[p]);
                    }
                }
            }
            #pragma unroll
            for (int p = 0; p < 4; ++p)
                if (s[p] < best[p]) { best[p] = s[p]; bi[p] = k; }
        }
        #pragma unroll
        for (int p = 0; p < 4; ++p) { rbest[p][t] = best[p]; ribst[p][t] = bi[p]; }
        __syncthreads();
        for (int st = 128; st; st >>= 1) {
            if (t < st) {
                #pragma unroll
                for (int p = 0; p < 4; ++p) {
                    double ov = rbest[p][t + st]; int oi = ribst[p][t + st];
                    if (ov < rbest[p][t] || (ov == rbest[p][t] && oi < ribst[p][t])) {
                        rbest[p][t] = ov; ribst[p][t] = oi;
                    }
                }
            }
            __syncthreads();
        }
        if (t < npx) {
            int n = full_list[g * 4 + t];
            min_idx[n] = ribst[t][0];
            min_d[n] = (float)rbest[t][0] - xsq[n];   // keep m1-convention
        }
        __syncthreads();
    }
}

// ---------- out: pure gather of quantized rows into NCHW ---------------------
__global__ __launch_bounds__(256) void out_kernel(
    const float* __restrict__ cb, const int* __restrict__ min_idx,
    float* __restrict__ out)
{
    int n = blockIdx.x * 256 + threadIdx.x;
    int b = n / HWIMG, hw = n % HWIMG;
    float* ob = out + (size_t)b * CC * HWIMG + hw;
    int k = min_idx[n];
    const float* er = cb + (size_t)k * CC;
    #pragma unroll 8
    for (int c = 0; c < CC; c += 4) {
        float4 q = *(const float4*)&er[c];
        ob[(size_t)(c + 0) * HWIMG] = q.x;
        ob[(size_t)(c + 1) * HWIMG] = q.y;
        ob[(size_t)(c + 2) * HWIMG] = q.z;
        ob[(size_t)(c + 3) * HWIMG] = q.w;
    }
}

// ---------- loss_reduce: sum (min_d + xsq) in fp64 ---------------------------
__global__ __launch_bounds__(256) void loss_reduce(
    const float* __restrict__ min_d, const float* __restrict__ xsq,
    double* __restrict__ partials)
{
    int n = blockIdx.x * 256 + threadIdx.x;
    double v = (double)min_d[n] + (double)xsq[n];
    __shared__ double sred[256];
    sred[threadIdx.x] = v;
    __syncthreads();
    for (int s = 128; s; s >>= 1) {
        if (threadIdx.x < (unsigned)s) sred[threadIdx.x] += sred[threadIdx.x + s];
        __syncthreads();
    }
    if (threadIdx.x == 0) partials[blockIdx.x] = sred[0];
}

__global__ void loss_kernel(const double* __restrict__ partials, float* __restrict__ out)
{
    if (threadIdx.x == 0 && blockIdx.x == 0) {
        double s = 0.0;
        for (int i = 0; i < 512; i++) s += partials[i];
        out[33554432] = (float)(1.25 * s / 33554432.0);
    }
}

// ---------- launch -----------------------------------------------------------
extern "C" void kernel_launch(void* const* d_in, const int* in_sizes, int n_in,
                              void* d_out, int out_size, void* d_ws, size_t ws_size,
                              hipStream_t stream)
{
    const float* x  = (const float*)d_in[0];
    const float* cb = (const float*)d_in[1];
    float* out = (float*)d_out;

    // x_frag (64 MB) lives in d_out; out_kernel rewrites d_out afterwards.
    char* x_frag = (char*)d_out;

    char* ws = (char*)d_ws;
    char*   e_prep    = (char*) (ws + 0);            //   524,288 B
    float*  esq       = (float*)(ws + 524288);       //     4,096 B
    int*    min_idx   = (int*)  (ws + 528384);       //   524,288 B
    int*    cnts      = (int*)  (ws + 1052672);      //        16 B
    int*    full_list = (int*)  (ws + 1052688);      //   131,072 B
    double* partials  = (double*)(ws + 1183760);     //     4,096 B
    float*  min_d     = (float*)(ws + 1187856);      //   524,288 B
    float*  xsq       = (float*)(ws + 1712144);      //   524,288 B

    prep_e       <<<KCODES, 256, 0, stream>>>(cb, e_prep, esq, cnts);
    prep_xT      <<<NPIX / 64, 256, 0, stream>>>(x, x_frag, xsq);
    dist_kernel  <<<512, 256, 0, stream>>>(x_frag, e_prep, esq,
                                           min_idx, min_d, cnts, full_list);
    recheck_full4<<<1024, 256, 0, stream>>>(x, cb, cnts, full_list,
                                            min_idx, min_d, xsq);
    out_kernel   <<<NPIX / 256, 256, 0, stream>>>(cb, min_idx, out);
    loss_reduce  <<<NPIX / 256, 256, 0, stream>>>(min_d, xsq, partials);
    loss_kernel  <<<1, 64, 0, stream>>>(partials, out);
}